// Round 1
// baseline (1183.725 us; speedup 1.0000x reference)
//
#include <hip/hip_runtime.h>
#include <cmath>

#define B_ 8
#define A_ 1024
#define N_ 64
#define G_ 50
#define F_ 128

__device__ __forceinline__ float sspf(float v) {
    // softplus(v) - log(2), numerically stable
    return fmaxf(v, 0.0f) + log1pf(__expf(-fabsf(v))) - 0.69314718055994530942f;
}

// xt[row, f] = sum_c x[row, c] * W_in2f[c, f]
__global__ __launch_bounds__(128) void xt_kernel(
    const float* __restrict__ x, const float* __restrict__ Win2f,
    float* __restrict__ xt)
{
    const int row = blockIdx.x;
    const int t = threadIdx.x;
    __shared__ float xr[F_];
    xr[t] = x[(size_t)row * F_ + t];
    __syncthreads();
    float acc = 0.f;
    #pragma unroll 16
    for (int c = 0; c < F_; ++c) acc = fmaf(xr[c], Win2f[c * F_ + t], acc);
    xt[(size_t)row * F_ + t] = acc;
}

__global__ __launch_bounds__(128) void cfconv_kernel(
    const float* __restrict__ xt,     // [B*A, F] pre-transformed x
    const float* __restrict__ mask,   // [B,A,N]
    const int*   __restrict__ nbr,    // [B,A,N]
    const float* __restrict__ fij,    // [B,A,N,G]
    const float* __restrict__ Wf1,    // [G,F]
    const float* __restrict__ bf1,    // [F]
    const float* __restrict__ Wf2,    // [F,F]
    const float* __restrict__ bf2,    // [F]
    const float* __restrict__ Wout,   // [F,F]
    const float* __restrict__ bout,   // [F]
    float* __restrict__ out)          // [B*A, F]
{
    const int ba = blockIdx.x;        // b*A + a
    const int b  = ba >> 10;          // A = 1024
    const int t  = threadIdx.x;       // owns output feature t throughout

    __shared__ float s_fij[N_ * G_];  // 12.8 KB
    __shared__ float s_H[N_][F_];     // 32 KB
    __shared__ float s_y[F_];
    __shared__ float s_mask[N_];
    __shared__ int   s_nbr[N_];

    // stage f_ij tile, mask, neighbors
    const float* fsrc = fij + (size_t)ba * (N_ * G_);
    for (int i = t; i < N_ * G_; i += 128) s_fij[i] = fsrc[i];
    if (t < N_) {
        s_mask[t] = mask[(size_t)ba * N_ + t];
        s_nbr[t]  = nbr[(size_t)ba * N_ + t];
    }

    // per-thread column of W_f1 in registers (K = 50)
    float w1[G_];
    #pragma unroll
    for (int g = 0; g < G_; ++g) w1[g] = Wf1[g * F_ + t];
    const float bias1 = bf1[t];
    __syncthreads();

    // GEMM1 + ssp -> H in LDS
    #pragma unroll 4
    for (int n = 0; n < N_; ++n) {
        float acc = bias1;
        #pragma unroll
        for (int g = 0; g < G_; ++g) acc = fmaf(s_fij[n * G_ + g], w1[g], acc);
        s_H[n][t] = sspf(acc);
    }
    __syncthreads();

    // GEMM2 fused with gather * mask * sum over neighbors
    const float bias2 = bf2[t];
    const float* xtb = xt + ((size_t)b * A_) * F_;
    float y = 0.f;
    for (int nt = 0; nt < N_; nt += 8) {
        float acc[8];
        #pragma unroll
        for (int j = 0; j < 8; ++j) acc[j] = bias2;
        for (int kk = 0; kk < F_; kk += 32) {
            float w[32];
            #pragma unroll
            for (int k = 0; k < 32; ++k) w[k] = Wf2[(kk + k) * F_ + t];
            #pragma unroll
            for (int j = 0; j < 8; ++j) {
                #pragma unroll
                for (int k = 0; k < 32; ++k)
                    acc[j] = fmaf(s_H[nt + j][kk + k], w[k], acc[j]);
            }
        }
        #pragma unroll
        for (int j = 0; j < 8; ++j) {
            const int n = nt + j;
            const float xv = xtb[(size_t)s_nbr[n] * F_ + t];
            y = fmaf(s_mask[n] * acc[j], xv, y);
        }
    }

    s_y[t] = y;
    __syncthreads();

    // final dense + ssp
    float acc = bout[t];
    #pragma unroll 16
    for (int k = 0; k < F_; ++k) acc = fmaf(s_y[k], Wout[k * F_ + t], acc);
    out[(size_t)ba * F_ + t] = sspf(acc);
}

extern "C" void kernel_launch(void* const* d_in, const int* in_sizes, int n_in,
                              void* d_out, int out_size, void* d_ws, size_t ws_size,
                              hipStream_t stream) {
    const float* x     = (const float*)d_in[0];
    const float* mask  = (const float*)d_in[1];
    const int*   nbr   = (const int*)d_in[2];
    const float* fij   = (const float*)d_in[3];
    const float* Wf1   = (const float*)d_in[4];
    const float* bf1   = (const float*)d_in[5];
    const float* Wf2   = (const float*)d_in[6];
    const float* bf2   = (const float*)d_in[7];
    const float* Win2f = (const float*)d_in[8];
    const float* Wout  = (const float*)d_in[9];
    const float* bout  = (const float*)d_in[10];
    float* out = (float*)d_out;
    float* xt  = (float*)d_ws;   // B*A*F floats = 4 MB scratch

    xt_kernel<<<B_ * A_, 128, 0, stream>>>(x, Win2f, xt);
    cfconv_kernel<<<B_ * A_, 128, 0, stream>>>(xt, mask, nbr, fij,
                                               Wf1, bf1, Wf2, bf2,
                                               Wout, bout, out);
}

// Round 2
// 114.177 us; speedup vs baseline: 10.3674x; 10.3674x over previous
//
#include <hip/hip_runtime.h>

#define B_ 8
#define A_ 1024
#define N_ 64
#define G_ 50
#define F_ 128

typedef __attribute__((ext_vector_type(8))) short bf16x8;
typedef __attribute__((ext_vector_type(4))) float f32x4;

__device__ __forceinline__ float sspf(float v) {
    // softplus(v) - log(2), stable: max(v,0) + log(1+exp(-|v|)) - log2
    return fmaxf(v, 0.f) + __logf(1.f + __expf(-fabsf(v))) - 0.69314718055994530942f;
}
__device__ __forceinline__ unsigned short f2bf(float f) {
    unsigned u = __float_as_uint(f);
    u += 0x7fffu + ((u >> 16) & 1u);
    return (unsigned short)(u >> 16);
}
__device__ __forceinline__ float bf2f(unsigned short h) {
    return __uint_as_float(((unsigned)h) << 16);
}

// Pack a [K x 128] fp32 weight into B-fragment order for mfma_f32_16x16x32_bf16:
// P[((ks*8+nt)*64 + lane)*8 + i] = W[(32ks + 8*(lane>>4) + i) * 128 + 16nt + (lane&15)]
__global__ __launch_bounds__(256) void pack_kernel(const float* __restrict__ W,
                                                   unsigned short* __restrict__ P,
                                                   int K, int nelem) {
    int id = blockIdx.x * 256 + threadIdx.x;
    if (id >= nelem) return;
    int i    = id & 7;
    int lane = (id >> 3) & 63;
    int nt   = (id >> 9) & 7;
    int ks   = id >> 12;
    int k = 32 * ks + 8 * (lane >> 4) + i;
    int f = 16 * nt + (lane & 15);
    P[id] = (k < K) ? f2bf(W[k * F_ + f]) : (unsigned short)0;
}

// out[R x 128] = (ACT? ssp : id)(A[R x 128] @ Bpacked + bias). 1 wave per 16 rows.
template <bool ACT, bool OUT_BF16>
__global__ __launch_bounds__(64) void rowgemm_kernel(
    const float* Afp, const unsigned short* __restrict__ Bp,
    const float* __restrict__ bias, void* outv)
{
    const int l  = threadIdx.x;
    const int r0 = blockIdx.x * 16;
    const bf16x8* Bv = (const bf16x8*)Bp;

    f32x4 acc[8];
    #pragma unroll
    for (int nt = 0; nt < 8; ++nt) acc[nt] = f32x4{0.f, 0.f, 0.f, 0.f};

    const int arow = r0 + (l & 15);
    const int koff = (l >> 4) * 8;
    #pragma unroll
    for (int ks = 0; ks < 4; ++ks) {
        const float* ap = Afp + (size_t)arow * F_ + ks * 32 + koff;
        float4 a0 = *(const float4*)ap;
        float4 a1 = *(const float4*)(ap + 4);
        bf16x8 af;
        af[0] = (short)f2bf(a0.x); af[1] = (short)f2bf(a0.y);
        af[2] = (short)f2bf(a0.z); af[3] = (short)f2bf(a0.w);
        af[4] = (short)f2bf(a1.x); af[5] = (short)f2bf(a1.y);
        af[6] = (short)f2bf(a1.z); af[7] = (short)f2bf(a1.w);
        #pragma unroll
        for (int nt = 0; nt < 8; ++nt) {
            bf16x8 bf = Bv[(ks * 8 + nt) * 64 + l];
            acc[nt] = __builtin_amdgcn_mfma_f32_16x16x32_bf16(af, bf, acc[nt], 0, 0, 0);
        }
    }
    #pragma unroll
    for (int nt = 0; nt < 8; ++nt) {
        int f = nt * 16 + (l & 15);
        float bv = bias ? bias[f] : 0.f;
        #pragma unroll
        for (int r = 0; r < 4; ++r) {
            int orow = r0 + (l >> 4) * 4 + r;
            float v = acc[nt][r] + bv;
            if (ACT) v = sspf(v);
            if (OUT_BF16) ((unsigned short*)outv)[(size_t)orow * F_ + f] = f2bf(v);
            else          ((float*)outv)[(size_t)orow * F_ + f] = v;
        }
    }
}

__global__ __launch_bounds__(256) void cfconv_main(
    const unsigned short* __restrict__ xt,   // [B*A][F] bf16 (pre-transformed x)
    const float* __restrict__ mask,          // [B,A,N]
    const int*   __restrict__ nbr,           // [B,A,N]
    const float* __restrict__ fij,           // [B,A,N,G]
    const unsigned short* __restrict__ W1p,  // packed [2][8][64][8]
    const float* __restrict__ bf1,
    const unsigned short* __restrict__ W2p,  // packed [4][8][64][8]
    const float* __restrict__ bf2,
    float* __restrict__ Y)                   // [B*A][F] pre-output accumulators
{
    const int ba = blockIdx.x;
    const int b  = ba >> 10;
    const int t  = threadIdx.x;
    const int w  = t >> 6;      // wave 0..3, owns f columns [32w, 32w+32)
    const int l  = t & 63;

    __shared__ unsigned short s_fp[4 * 2 * 64 * 8];  // f_ij A-frags, 8 KB
    __shared__ unsigned short s_hp[4 * 4 * 64 * 8];  // H A-frags, 16 KB
    __shared__ float s_mask[N_];
    __shared__ int   s_nbr[N_];
    __shared__ float s_y[F_];

    if (t < N_) {
        s_mask[t] = mask[(size_t)ba * N_ + t];
        s_nbr[t]  = nbr[(size_t)ba * N_ + t];
    }

    // ---- stage f_ij (fp32, K=50) -> packed bf16 A-frags (K padded to 64) ----
    {
        const int m  = t >> 2;
        const int g0 = (t & 3) * 16;
        const float* src = fij + (size_t)ba * (N_ * G_) + m * G_;
        float vals[16];
        #pragma unroll
        for (int j = 0; j < 16; j += 2) {
            int g = g0 + j;
            if (g + 1 < G_) { float2 v = *(const float2*)(src + g); vals[j] = v.x; vals[j+1] = v.y; }
            else { vals[j] = (g < G_) ? src[g] : 0.f; vals[j+1] = 0.f; }
        }
        #pragma unroll
        for (int j = 0; j < 16; ++j) {
            int g = g0 + j;
            int lane = (m & 15) + 16 * ((g >> 3) & 3);
            int idx = (((m >> 4) * 2 + (g >> 5)) * 64 + lane) * 8 + (g & 7);
            s_fp[idx] = f2bf(vals[j]);
        }
    }
    __syncthreads();

    // ---- GEMM1: H = ssp(fij @ W1 + b1), wave computes nt = 2w, 2w+1 ----
    const bf16x8* fv  = (const bf16x8*)s_fp;
    const bf16x8* w1v = (const bf16x8*)W1p;
    f32x4 acc1[4][2];
    #pragma unroll
    for (int mt = 0; mt < 4; ++mt)
        #pragma unroll
        for (int j = 0; j < 2; ++j) acc1[mt][j] = f32x4{0.f, 0.f, 0.f, 0.f};

    #pragma unroll
    for (int ks = 0; ks < 2; ++ks) {
        bf16x8 a[4];
        #pragma unroll
        for (int mt = 0; mt < 4; ++mt) a[mt] = fv[(mt * 2 + ks) * 64 + l];
        #pragma unroll
        for (int j = 0; j < 2; ++j) {
            bf16x8 bv = w1v[(ks * 8 + 2 * w + j) * 64 + l];
            #pragma unroll
            for (int mt = 0; mt < 4; ++mt)
                acc1[mt][j] = __builtin_amdgcn_mfma_f32_16x16x32_bf16(a[mt], bv, acc1[mt][j], 0, 0, 0);
        }
    }
    float b1v[2] = { bf1[32 * w + (l & 15)], bf1[32 * w + 16 + (l & 15)] };
    #pragma unroll
    for (int mt = 0; mt < 4; ++mt)
        #pragma unroll
        for (int j = 0; j < 2; ++j) {
            int f = 32 * w + 16 * j + (l & 15);
            int lane_f = 16 * ((f >> 3) & 3);
            #pragma unroll
            for (int r = 0; r < 4; ++r) {
                int mrow = (l >> 4) * 4 + r;   // m & 15
                float h = sspf(acc1[mt][j][r] + b1v[j]);
                int idx = ((mt * 4 + (f >> 5)) * 64 + mrow + lane_f) * 8 + (f & 7);
                s_hp[idx] = f2bf(h);
            }
        }
    __syncthreads();

    // ---- GEMM2: filter = H @ W2 + b2, fused gather*mask*rowsum ----
    const bf16x8* hv  = (const bf16x8*)s_hp;
    const bf16x8* w2v = (const bf16x8*)W2p;
    f32x4 acc2[4][2];
    #pragma unroll
    for (int mt = 0; mt < 4; ++mt)
        #pragma unroll
        for (int j = 0; j < 2; ++j) acc2[mt][j] = f32x4{0.f, 0.f, 0.f, 0.f};

    #pragma unroll
    for (int ks = 0; ks < 4; ++ks) {
        bf16x8 a[4];
        #pragma unroll
        for (int mt = 0; mt < 4; ++mt) a[mt] = hv[(mt * 4 + ks) * 64 + l];
        #pragma unroll
        for (int j = 0; j < 2; ++j) {
            bf16x8 bv = w2v[(ks * 8 + 2 * w + j) * 64 + l];
            #pragma unroll
            for (int mt = 0; mt < 4; ++mt)
                acc2[mt][j] = __builtin_amdgcn_mfma_f32_16x16x32_bf16(a[mt], bv, acc2[mt][j], 0, 0, 0);
        }
    }

    float b2v[2] = { bf2[32 * w + (l & 15)], bf2[32 * w + 16 + (l & 15)] };
    const unsigned short* xb = xt + ((size_t)(b << 10)) * F_;
    #pragma unroll
    for (int j = 0; j < 2; ++j) {
        int f = 32 * w + 16 * j + (l & 15);
        float p = 0.f;
        #pragma unroll
        for (int mt = 0; mt < 4; ++mt)
            #pragma unroll
            for (int r = 0; r < 4; ++r) {
                int m = mt * 16 + (l >> 4) * 4 + r;
                float filt = acc2[mt][j][r] + b2v[j];
                float xv = bf2f(xb[(size_t)s_nbr[m] * F_ + f]);
                p = fmaf(s_mask[m] * filt, xv, p);
            }
        p += __shfl_xor(p, 16, 64);
        p += __shfl_xor(p, 32, 64);
        if (l < 16) s_y[f] = p;
    }
    __syncthreads();
    if (t < F_) Y[(size_t)ba * F_ + t] = s_y[t];
}

extern "C" void kernel_launch(void* const* d_in, const int* in_sizes, int n_in,
                              void* d_out, int out_size, void* d_ws, size_t ws_size,
                              hipStream_t stream) {
    const float* x     = (const float*)d_in[0];
    const float* mask  = (const float*)d_in[1];
    const int*   nbr   = (const int*)d_in[2];
    const float* fij   = (const float*)d_in[3];
    const float* Wf1   = (const float*)d_in[4];
    const float* bf1   = (const float*)d_in[5];
    const float* Wf2   = (const float*)d_in[6];
    const float* bf2   = (const float*)d_in[7];
    const float* Win2f = (const float*)d_in[8];
    const float* Wout  = (const float*)d_in[9];
    const float* bout  = (const float*)d_in[10];
    float* out = (float*)d_out;

    // ws layout
    char* ws = (char*)d_ws;
    unsigned short* W1p   = (unsigned short*)(ws);            // 8192 u16  = 16 KB
    unsigned short* W2p   = (unsigned short*)(ws + 16384);    // 16384 u16 = 32 KB
    unsigned short* Winp  = (unsigned short*)(ws + 49152);    // 32 KB
    unsigned short* Woutp = (unsigned short*)(ws + 81920);    // 32 KB
    unsigned short* xt    = (unsigned short*)(ws + 114688);   // B*A*F bf16 = 2 MB

    pack_kernel<<<32, 256, 0, stream>>>(Wf1,   W1p,   G_, 8192);
    pack_kernel<<<64, 256, 0, stream>>>(Wf2,   W2p,   F_, 16384);
    pack_kernel<<<64, 256, 0, stream>>>(Win2f, Winp,  F_, 16384);
    pack_kernel<<<64, 256, 0, stream>>>(Wout,  Woutp, F_, 16384);

    // xt = bf16(x @ W_in2f)
    rowgemm_kernel<false, true><<<B_ * A_ / 16, 64, 0, stream>>>(x, Winp, nullptr, xt);

    // main fused CFConv: writes Y (pre-output) into d_out
    cfconv_main<<<B_ * A_, 256, 0, stream>>>(xt, mask, nbr, fij, W1p, bf1, W2p, bf2, out);

    // out = ssp(Y @ Wout + bout), in-place on d_out (each block owns its rows)
    rowgemm_kernel<true, false><<<B_ * A_ / 16, 64, 0, stream>>>(out, Woutp, bout, out);
}

// Round 3
// 103.931 us; speedup vs baseline: 11.3896x; 1.0986x over previous
//
#include <hip/hip_runtime.h>

#define B_ 8
#define A_ 1024
#define N_ 64
#define G_ 50
#define F_ 128

typedef __attribute__((ext_vector_type(8))) short bf16x8;
typedef __attribute__((ext_vector_type(4))) float f32x4;

__device__ __forceinline__ float sspf(float v) {
    return fmaxf(v, 0.f) + __logf(1.f + __expf(-fabsf(v))) - 0.69314718055994530942f;
}
__device__ __forceinline__ unsigned short f2bf(float f) {
    unsigned u = __float_as_uint(f);
    u += 0x7fffu + ((u >> 16) & 1u);
    return (unsigned short)(u >> 16);
}
__device__ __forceinline__ float bf2f(unsigned short h) {
    return __uint_as_float(((unsigned)h) << 16);
}
__device__ __forceinline__ unsigned cvt_pk(float lo, float hi) {
    unsigned r;
    asm("v_cvt_pk_bf16_f32 %0, %1, %2" : "=v"(r) : "v"(lo), "v"(hi));
    return r;
}

// Pack a [K x 128] fp32 weight into B-fragment order for mfma_f32_16x16x32_bf16:
// P[((ks*8+nt)*64 + lane)*8 + i] = W[(32ks + 8*(lane>>4) + i) * 128 + 16nt + (lane&15)]
__global__ __launch_bounds__(256) void pack_kernel(const float* __restrict__ W,
                                                   unsigned short* __restrict__ P,
                                                   int K, int nelem) {
    int id = blockIdx.x * 256 + threadIdx.x;
    if (id >= nelem) return;
    int i    = id & 7;
    int lane = (id >> 3) & 63;
    int nt   = (id >> 9) & 7;
    int ks   = id >> 12;
    int k = 32 * ks + 8 * (lane >> 4) + i;
    int f = 16 * nt + (lane & 15);
    P[id] = (k < K) ? f2bf(W[k * F_ + f]) : (unsigned short)0;
}

// out[R x 128] = (ACT? ssp : id)(A[R x 128] @ Bpacked + bias). 1 wave per 16 rows.
template <bool ACT, bool OUT_BF16>
__global__ __launch_bounds__(64) void rowgemm_kernel(
    const float* Afp, const unsigned short* __restrict__ Bp,
    const float* __restrict__ bias, void* outv)
{
    const int l  = threadIdx.x;
    const int r0 = blockIdx.x * 16;
    const bf16x8* Bv = (const bf16x8*)Bp;

    f32x4 acc[8];
    #pragma unroll
    for (int nt = 0; nt < 8; ++nt) acc[nt] = f32x4{0.f, 0.f, 0.f, 0.f};

    const int arow = r0 + (l & 15);
    const int koff = (l >> 4) * 8;
    #pragma unroll
    for (int ks = 0; ks < 4; ++ks) {
        const float* ap = Afp + (size_t)arow * F_ + ks * 32 + koff;
        float4 a0 = *(const float4*)ap;
        float4 a1 = *(const float4*)(ap + 4);
        bf16x8 af;
        af[0] = (short)f2bf(a0.x); af[1] = (short)f2bf(a0.y);
        af[2] = (short)f2bf(a0.z); af[3] = (short)f2bf(a0.w);
        af[4] = (short)f2bf(a1.x); af[5] = (short)f2bf(a1.y);
        af[6] = (short)f2bf(a1.z); af[7] = (short)f2bf(a1.w);
        #pragma unroll
        for (int nt = 0; nt < 8; ++nt) {
            bf16x8 bf = Bv[(ks * 8 + nt) * 64 + l];
            acc[nt] = __builtin_amdgcn_mfma_f32_16x16x32_bf16(af, bf, acc[nt], 0, 0, 0);
        }
    }
    #pragma unroll
    for (int nt = 0; nt < 8; ++nt) {
        int f = nt * 16 + (l & 15);
        float bv = bias ? bias[f] : 0.f;
        #pragma unroll
        for (int r = 0; r < 4; ++r) {
            int orow = r0 + (l >> 4) * 4 + r;
            float v = acc[nt][r] + bv;
            if (ACT) v = sspf(v);
            if (OUT_BF16) ((unsigned short*)outv)[(size_t)orow * F_ + f] = f2bf(v);
            else          ((float*)outv)[(size_t)orow * F_ + f] = v;
        }
    }
}

__global__ __launch_bounds__(256, 4) void cfconv_main(
    const unsigned short* __restrict__ xt,   // [B*A][F] bf16 (pre-transformed x)
    const float* __restrict__ mask,          // [B,A,N]
    const int*   __restrict__ nbr,           // [B,A,N]
    const float* __restrict__ fij,           // [B,A,N,G]
    const unsigned short* __restrict__ W1p,  // packed [2][8][64][8]
    const float* __restrict__ bf1,
    const unsigned short* __restrict__ W2p,  // packed [4][8][64][8]
    const float* __restrict__ bf2,
    float* __restrict__ Y)                   // [B*A][F] pre-output accumulators
{
    const int ba  = blockIdx.x;
    const int b   = ba >> 10;
    const int t   = threadIdx.x;
    const int w   = t >> 6;
    const int l   = t & 63;
    const int l16 = l & 15;
    const int q   = l >> 4;

    __shared__ unsigned short s_hp[8192];      // H A-frags (16KB); [4096..8192) aliases fij frags
    __shared__ unsigned short s_xg[64 * 136];  // gathered xt rows, stride 136 u16
    __shared__ float s_mask[N_];
    __shared__ int   s_nbr[N_];

    unsigned short* s_fp = s_hp + 4096;

    // ---- mask/nbr -> regs ----
    float mk = 0.f; int nb = 0;
    if (t < N_) { mk = mask[(size_t)ba * N_ + t]; nb = nbr[(size_t)ba * N_ + t]; }

    // ---- f_ij staging: frag-direct, this wave stages mt = w ----
    {
        const float* frow = fij + (size_t)ba * (N_ * G_) + (16 * w + l16) * G_;
        const int g0 = 8 * q;
        {   // ks = 0: g in [g0, g0+8), all valid (< 32)
            float2 a0 = *(const float2*)(frow + g0);
            float2 a1 = *(const float2*)(frow + g0 + 2);
            float2 a2 = *(const float2*)(frow + g0 + 4);
            float2 a3 = *(const float2*)(frow + g0 + 6);
            uint4 pk;
            pk.x = cvt_pk(a0.x, a0.y);
            pk.y = cvt_pk(a1.x, a1.y);
            pk.z = cvt_pk(a2.x, a2.y);
            pk.w = cvt_pk(a3.x, a3.y);
            *(uint4*)(&s_fp[((w * 2 + 0) * 64 + l) * 8]) = pk;
        }
        {   // ks = 1: g in [32+g0, 32+g0+8), zero-pad g >= 50
            float v[8];
            if (q < 2) {
                const float* p = frow + 32 + g0;
                float2 a0 = *(const float2*)(p);
                float2 a1 = *(const float2*)(p + 2);
                float2 a2 = *(const float2*)(p + 4);
                float2 a3 = *(const float2*)(p + 6);
                v[0]=a0.x; v[1]=a0.y; v[2]=a1.x; v[3]=a1.y;
                v[4]=a2.x; v[5]=a2.y; v[6]=a3.x; v[7]=a3.y;
            } else if (q == 2) {
                float2 a0 = *(const float2*)(frow + 48);
                v[0]=a0.x; v[1]=a0.y;
                v[2]=0.f; v[3]=0.f; v[4]=0.f; v[5]=0.f; v[6]=0.f; v[7]=0.f;
            } else {
                #pragma unroll
                for (int i = 0; i < 8; ++i) v[i] = 0.f;
            }
            uint4 pk;
            pk.x = cvt_pk(v[0], v[1]);
            pk.y = cvt_pk(v[2], v[3]);
            pk.z = cvt_pk(v[4], v[5]);
            pk.w = cvt_pk(v[6], v[7]);
            *(uint4*)(&s_fp[((w * 2 + 1) * 64 + l) * 8]) = pk;
        }
    }

    if (t < N_) { s_mask[t] = mk; s_nbr[t] = nb; }
    __syncthreads();   // B1: s_fp, s_nbr, s_mask ready

    // ---- gathered-x loads -> regs (fly under GEMM1) ----
    uint4 xg[4];
    #pragma unroll
    for (int k = 0; k < 4; ++k) {
        int c = k * 256 + t;
        int row = s_nbr[c >> 4];
        xg[k] = *(const uint4*)(xt + (((size_t)(b << 10) + row) * F_ + (c & 15) * 8));
    }

    // ---- GEMM1: H = ssp(fij @ W1 + b1) ----
    const bf16x8* fv  = (const bf16x8*)s_fp;
    const bf16x8* w1v = (const bf16x8*)W1p;
    f32x4 acc1[4][2];
    #pragma unroll
    for (int mt = 0; mt < 4; ++mt)
        #pragma unroll
        for (int j = 0; j < 2; ++j) acc1[mt][j] = f32x4{0.f, 0.f, 0.f, 0.f};

    #pragma unroll
    for (int ks = 0; ks < 2; ++ks) {
        bf16x8 a[4];
        #pragma unroll
        for (int mt = 0; mt < 4; ++mt) a[mt] = fv[(mt * 2 + ks) * 64 + l];
        #pragma unroll
        for (int j = 0; j < 2; ++j) {
            bf16x8 bv = w1v[(ks * 8 + 2 * w + j) * 64 + l];
            #pragma unroll
            for (int mt = 0; mt < 4; ++mt)
                acc1[mt][j] = __builtin_amdgcn_mfma_f32_16x16x32_bf16(a[mt], bv, acc1[mt][j], 0, 0, 0);
        }
    }
    __syncthreads();   // B2: s_fp reads done -> alias region writable

    // ---- park gathered rows in LDS ----
    #pragma unroll
    for (int k = 0; k < 4; ++k) {
        int c = k * 256 + t;
        *(uint4*)(&s_xg[(c >> 4) * 136 + (c & 15) * 8]) = xg[k];
    }

    // ---- epilogue: ssp -> pi-permuted H A-frags (bank-conflict-free writes) ----
    const float b1lo = bf1[32 * w + l16];
    const float b1hi = bf1[32 * w + 16 + l16];
    const int ebase = (w * 64 + q + 4 * (l16 >> 3)) * 8 + (l16 & 7);
    #pragma unroll
    for (int mt = 0; mt < 4; ++mt)
        #pragma unroll
        for (int j = 0; j < 2; ++j) {
            float bj = j ? b1hi : b1lo;
            float h0 = sspf(acc1[mt][j][0] + bj);
            float h1 = sspf(acc1[mt][j][1] + bj);
            float h2 = sspf(acc1[mt][j][2] + bj);
            float h3 = sspf(acc1[mt][j][3] + bj);
            unsigned pk01 = cvt_pk(h0, h1);
            unsigned pk23 = cvt_pk(h2, h3);
            int base = ebase + mt * 2048 + j * 64;
            s_hp[base      ] = (unsigned short)(pk01 & 0xffffu);
            s_hp[base + 128] = (unsigned short)(pk01 >> 16);
            s_hp[base + 256] = (unsigned short)(pk23 & 0xffffu);
            s_hp[base + 384] = (unsigned short)(pk23 >> 16);
        }
    __syncthreads();   // B3

    // ---- GEMM2: filter = H @ W2 + b2 ----
    const bf16x8* hv  = (const bf16x8*)s_hp;
    const bf16x8* w2v = (const bf16x8*)W2p;
    f32x4 acc2[4][2];
    #pragma unroll
    for (int mt = 0; mt < 4; ++mt)
        #pragma unroll
        for (int j = 0; j < 2; ++j) acc2[mt][j] = f32x4{0.f, 0.f, 0.f, 0.f};

    const int rdentry = (l16 >> 2) + 4 * (q & 1) + 8 * (q >> 1) + 16 * (l16 & 3);
    #pragma unroll
    for (int ks = 0; ks < 4; ++ks) {
        bf16x8 a[4];
        #pragma unroll
        for (int mt = 0; mt < 4; ++mt) a[mt] = hv[(mt * 4 + ks) * 64 + rdentry];
        #pragma unroll
        for (int j = 0; j < 2; ++j) {
            bf16x8 bv = w2v[(ks * 8 + 2 * w + j) * 64 + l];
            #pragma unroll
            for (int mt = 0; mt < 4; ++mt)
                acc2[mt][j] = __builtin_amdgcn_mfma_f32_16x16x32_bf16(a[mt], bv, acc2[mt][j], 0, 0, 0);
        }
    }

    // ---- gather * mask * rowsum (all LDS, immediate offsets) ----
    const float b2lo = bf2[32 * w + l16];
    const float b2hi = bf2[32 * w + 16 + l16];
    float p0 = 0.f, p1 = 0.f;
    const int xgb = 544 * q + 32 * w + l16;
    #pragma unroll
    for (int mt = 0; mt < 4; ++mt)
        #pragma unroll
        for (int r = 0; r < 4; ++r) {
            int m = 16 * mt + 4 * q + r;
            float msk = s_mask[m];
            float f0 = acc2[mt][0][r] + b2lo;
            float f1 = acc2[mt][1][r] + b2hi;
            float x0 = bf2f(s_xg[xgb + 2176 * mt + 136 * r]);
            float x1 = bf2f(s_xg[xgb + 2176 * mt + 136 * r + 16]);
            p0 = fmaf(msk * f0, x0, p0);
            p1 = fmaf(msk * f1, x1, p1);
        }
    p0 += __shfl_xor(p0, 16, 64); p0 += __shfl_xor(p0, 32, 64);
    p1 += __shfl_xor(p1, 16, 64); p1 += __shfl_xor(p1, 32, 64);
    if (l < 16) {
        float* yp = Y + (size_t)ba * F_ + 32 * w + l16;
        yp[0]  = p0;
        yp[16] = p1;
    }
}

extern "C" void kernel_launch(void* const* d_in, const int* in_sizes, int n_in,
                              void* d_out, int out_size, void* d_ws, size_t ws_size,
                              hipStream_t stream) {
    const float* x     = (const float*)d_in[0];
    const float* mask  = (const float*)d_in[1];
    const int*   nbr   = (const int*)d_in[2];
    const float* fij   = (const float*)d_in[3];
    const float* Wf1   = (const float*)d_in[4];
    const float* bf1   = (const float*)d_in[5];
    const float* Wf2   = (const float*)d_in[6];
    const float* bf2   = (const float*)d_in[7];
    const float* Win2f = (const float*)d_in[8];
    const float* Wout  = (const float*)d_in[9];
    const float* bout  = (const float*)d_in[10];
    float* out = (float*)d_out;

    // ws layout
    char* ws = (char*)d_ws;
    unsigned short* W1p   = (unsigned short*)(ws);            // 8192 u16  = 16 KB
    unsigned short* W2p   = (unsigned short*)(ws + 16384);    // 16384 u16 = 32 KB
    unsigned short* Winp  = (unsigned short*)(ws + 49152);    // 32 KB
    unsigned short* Woutp = (unsigned short*)(ws + 81920);    // 32 KB
    unsigned short* xt    = (unsigned short*)(ws + 114688);   // B*A*F bf16 = 2 MB

    pack_kernel<<<32, 256, 0, stream>>>(Wf1,   W1p,   G_, 8192);
    pack_kernel<<<64, 256, 0, stream>>>(Wf2,   W2p,   F_, 16384);
    pack_kernel<<<64, 256, 0, stream>>>(Win2f, Winp,  F_, 16384);
    pack_kernel<<<64, 256, 0, stream>>>(Wout,  Woutp, F_, 16384);

    // xt = bf16(x @ W_in2f)
    rowgemm_kernel<false, true><<<B_ * A_ / 16, 64, 0, stream>>>(x, Winp, nullptr, xt);

    // main fused CFConv: writes Y (pre-output) into d_out
    cfconv_main<<<B_ * A_, 256, 0, stream>>>(xt, mask, nbr, fij, W1p, bf1, W2p, bf2, out);

    // out = ssp(Y @ Wout + bout), in-place on d_out (each block owns its rows)
    rowgemm_kernel<true, false><<<B_ * A_ / 16, 64, 0, stream>>>(out, Woutp, bout, out);
}